// Round 1
// baseline (144.945 us; speedup 1.0000x reference)
//
#include <hip/hip_runtime.h>
#include <math.h>

#define NUM_FREQS   64
#define NUM_BINS    128
#define NUM_QUERIES 32768
#define HEAD_DIM    128
#define EPS         1e-8f
#define NQ          8   // queries per block in main kernel

typedef float f32x8 __attribute__((ext_vector_type(8)));

// ---------------------------------------------------------------------------
// Prep 1: pack probe-side constants, transposed to [f][b] for coalesced loads.
// probeT[f*128+b] = { P_real[b][f], P_imag[b][f], -softplus(w[b][f]), mw[b][f] }
// ---------------------------------------------------------------------------
__global__ void prep_probe(const float* __restrict__ rp,
                           const float* __restrict__ wraw,
                           const float* __restrict__ mw,
                           float4* __restrict__ probeT) {
    int tid = blockIdx.x * blockDim.x + threadIdx.x;   // tid = f*128 + b
    if (tid >= NUM_FREQS * NUM_BINS) return;
    int f = tid >> 7;
    int b = tid & 127;
    float pr = rp[b * HEAD_DIM + f];
    float pi = rp[b * HEAD_DIM + NUM_FREQS + f];
    float w  = wraw[b * NUM_FREQS + f];
    float sp = fmaxf(w, 0.0f) + log1pf(expf(-fabsf(w)));   // stable softplus
    float m  = mw[b * NUM_FREQS + f];
    probeT[tid] = make_float4(pr, pi, -sp, m);
}

// ---------------------------------------------------------------------------
// Prep 2: normalize Q rows; write transposed QrT/QiT/QmT[f][q] so the main
// kernel can fetch 8 consecutive queries per f with one scalar load each.
// ---------------------------------------------------------------------------
__global__ void prep_q(const float* __restrict__ Q,
                       float* __restrict__ QrT,
                       float* __restrict__ QiT,
                       float* __restrict__ QmT) {
    int q = blockIdx.x * blockDim.x + threadIdx.x;
    if (q >= NUM_QUERIES) return;
    const float4* Qrow = reinterpret_cast<const float4*>(Q + (size_t)q * HEAD_DIM);
    float4 buf[32];
    float s = 0.0f;
    #pragma unroll
    for (int i = 0; i < 32; i++) {
        float4 v = Qrow[i];
        buf[i] = v;
        s = fmaf(v.x, v.x, fmaf(v.y, v.y, fmaf(v.z, v.z, fmaf(v.w, v.w, s))));
    }
    float inv = 1.0f / (__builtin_amdgcn_sqrtf(s) + EPS);
    #pragma unroll
    for (int i = 0; i < 16; i++) {
        float4 r  = buf[i];        // dims 4i..4i+3      -> real part
        float4 im = buf[16 + i];   // dims 64+4i..64+4i+3 -> imag part
        float rr[4] = { r.x,  r.y,  r.z,  r.w  };
        float ii[4] = { im.x, im.y, im.z, im.w };
        #pragma unroll
        for (int k = 0; k < 4; k++) {
            float qr = rr[k] * inv;
            float qi = ii[k] * inv;
            float qm = __builtin_amdgcn_sqrtf(fmaf(qr, qr, fmaf(qi, qi, EPS)));
            int f = 4 * i + k;
            QrT[(size_t)f * NUM_QUERIES + q] = qr;   // coalesced: lanes = q
            QiT[(size_t)f * NUM_QUERIES + q] = qi;
            QmT[(size_t)f * NUM_QUERIES + q] = qm;
        }
    }
}

// ---------------------------------------------------------------------------
// Main: block = 128 threads (one per bin), each block owns NQ=8 queries.
// q-side values are wave-uniform -> scalar loads (s_load_dwordx8) on SMEM pipe.
// probe side is one coalesced float4 vector load per f.
// ---------------------------------------------------------------------------
__global__ __launch_bounds__(NUM_BINS) void main_kernel(
        const float4* __restrict__ probeT,
        const float*  __restrict__ QrT,
        const float*  __restrict__ QiT,
        const float*  __restrict__ QmT,
        const float*  __restrict__ bias,
        float*        __restrict__ out) {
    const int b     = threadIdx.x;
    const int qbase = blockIdx.x * NQ;

    float acc[NQ];
    #pragma unroll
    for (int j = 0; j < NQ; j++) acc[j] = 0.0f;

    #pragma unroll 2
    for (int f = 0; f < NUM_FREQS; f++) {
        float4 p = probeT[f * NUM_BINS + b];                       // vector, coalesced
        f32x8 qr = *reinterpret_cast<const f32x8*>(QrT + (size_t)f * NUM_QUERIES + qbase);
        f32x8 qi = *reinterpret_cast<const f32x8*>(QiT + (size_t)f * NUM_QUERIES + qbase);
        f32x8 qm = *reinterpret_cast<const f32x8*>(QmT + (size_t)f * NUM_QUERIES + qbase);
        #pragma unroll
        for (int j = 0; j < NQ; j++) {
            float er = p.x - qr[j];
            float ei = p.y - qi[j];
            float d  = __builtin_amdgcn_sqrtf(fmaf(er, er, fmaf(ei, ei, EPS)));
            acc[j] = fmaf(d, p.z, fmaf(qm[j], p.w, acc[j]));
        }
    }

    float bb = bias[b];
    #pragma unroll
    for (int j = 0; j < NQ; j++)
        out[(size_t)(qbase + j) * NUM_BINS + b] = acc[j] + bb;     // coalesced stores
}

// ---------------------------------------------------------------------------
// Fallback (only if ws_size is too small): fully self-contained, slower.
// block = 128 threads (bins), one block per query.
// ---------------------------------------------------------------------------
__global__ void fallback_kernel(const float* __restrict__ Q,
                                const float* __restrict__ rp,
                                const float* __restrict__ wraw,
                                const float* __restrict__ mw,
                                const float* __restrict__ bias,
                                float* __restrict__ out) {
    __shared__ float qn[HEAD_DIM];
    __shared__ float qmag[NUM_FREQS];
    __shared__ float red[NUM_BINS];
    const int t = threadIdx.x;
    const int q = blockIdx.x;

    float v = Q[(size_t)q * HEAD_DIM + t];
    red[t] = v * v;
    __syncthreads();
    for (int s = 64; s > 0; s >>= 1) {
        if (t < s) red[t] += red[t + s];
        __syncthreads();
    }
    float inv = 1.0f / (__builtin_amdgcn_sqrtf(red[0]) + EPS);
    qn[t] = v * inv;
    __syncthreads();
    if (t < NUM_FREQS) {
        float a = qn[t], c = qn[t + NUM_FREQS];
        qmag[t] = __builtin_amdgcn_sqrtf(fmaf(a, a, fmaf(c, c, EPS)));
    }
    __syncthreads();

    const int b = t;
    float acc = 0.0f;
    for (int f = 0; f < NUM_FREQS; f++) {
        float pr = rp[(size_t)b * HEAD_DIM + f];
        float pi = rp[(size_t)b * HEAD_DIM + NUM_FREQS + f];
        float w  = wraw[(size_t)b * NUM_FREQS + f];
        float ew = -(fmaxf(w, 0.0f) + log1pf(expf(-fabsf(w))));
        float er = pr - qn[f];
        float ei = pi - qn[f + NUM_FREQS];
        float d  = __builtin_amdgcn_sqrtf(fmaf(er, er, fmaf(ei, ei, EPS)));
        acc = fmaf(d, ew, fmaf(qmag[f], mw[(size_t)b * NUM_FREQS + f], acc));
    }
    out[(size_t)q * NUM_BINS + b] = acc + bias[b];
}

// ---------------------------------------------------------------------------
extern "C" void kernel_launch(void* const* d_in, const int* in_sizes, int n_in,
                              void* d_out, int out_size, void* d_ws, size_t ws_size,
                              hipStream_t stream) {
    const float* Q    = (const float*)d_in[0];
    const float* rp   = (const float*)d_in[1];
    const float* wraw = (const float*)d_in[2];
    const float* mw   = (const float*)d_in[3];
    const float* bias = (const float*)d_in[4];
    float* out = (float*)d_out;

    const size_t probeBytes = (size_t)NUM_FREQS * NUM_BINS * sizeof(float4);  // 128 KiB
    const size_t qtBytes    = (size_t)NUM_FREQS * NUM_QUERIES * sizeof(float); // 8 MiB
    const size_t need       = probeBytes + 3 * qtBytes;

    if (ws_size >= need) {
        float4* probeT = (float4*)d_ws;
        float*  QrT    = (float*)((char*)d_ws + probeBytes);
        float*  QiT    = QrT + (size_t)NUM_FREQS * NUM_QUERIES;
        float*  QmT    = QiT + (size_t)NUM_FREQS * NUM_QUERIES;

        hipLaunchKernelGGL(prep_probe, dim3((NUM_FREQS * NUM_BINS + 255) / 256),
                           dim3(256), 0, stream, rp, wraw, mw, probeT);
        hipLaunchKernelGGL(prep_q, dim3(NUM_QUERIES / 256), dim3(256), 0, stream,
                           Q, QrT, QiT, QmT);
        hipLaunchKernelGGL(main_kernel, dim3(NUM_QUERIES / NQ), dim3(NUM_BINS), 0,
                           stream, probeT, QrT, QiT, QmT, bias, out);
    } else {
        hipLaunchKernelGGL(fallback_kernel, dim3(NUM_QUERIES), dim3(NUM_BINS), 0,
                           stream, Q, rp, wraw, mw, bias, out);
    }
}

// Round 2
// 94.418 us; speedup vs baseline: 1.5351x; 1.5351x over previous
//
#include <hip/hip_runtime.h>
#include <math.h>

#define NUM_FREQS   64
#define NUM_BINS    128
#define NUM_QUERIES 32768
#define HEAD_DIM    128
#define EPS         1e-8f
#define NQ          16   // queries per block in main kernel

typedef float f32x16 __attribute__((ext_vector_type(16)));

// ---------------------------------------------------------------------------
// Prep 1: pack probe-side constants, transposed to [f][b] for coalesced loads.
// probeT[f*128+b] = { P_real[b][f], P_imag[b][f], -softplus(w[b][f]), mw[b][f] }
// ---------------------------------------------------------------------------
__global__ void prep_probe(const float* __restrict__ rp,
                           const float* __restrict__ wraw,
                           const float* __restrict__ mw,
                           float4* __restrict__ probeT) {
    int tid = blockIdx.x * blockDim.x + threadIdx.x;   // tid = f*128 + b
    if (tid >= NUM_FREQS * NUM_BINS) return;
    int f = tid >> 7;
    int b = tid & 127;
    float pr = rp[b * HEAD_DIM + f];
    float pi = rp[b * HEAD_DIM + NUM_FREQS + f];
    float w  = wraw[b * NUM_FREQS + f];
    float sp = fmaxf(w, 0.0f) + log1pf(expf(-fabsf(w)));   // stable softplus
    float m  = mw[b * NUM_FREQS + f];
    probeT[tid] = make_float4(pr, pi, -sp, m);
}

// ---------------------------------------------------------------------------
// Prep 2: normalize Q rows; write transposed QrT/QiT/QmT[f][q] so the main
// kernel can fetch NQ consecutive queries per f with one (scalar) load each.
// ---------------------------------------------------------------------------
__global__ void prep_q(const float* __restrict__ Q,
                       float* __restrict__ QrT,
                       float* __restrict__ QiT,
                       float* __restrict__ QmT) {
    int q = blockIdx.x * blockDim.x + threadIdx.x;
    if (q >= NUM_QUERIES) return;
    const float4* Qrow = reinterpret_cast<const float4*>(Q + (size_t)q * HEAD_DIM);
    float4 buf[32];
    float s = 0.0f;
    #pragma unroll
    for (int i = 0; i < 32; i++) {
        float4 v = Qrow[i];
        buf[i] = v;
        s = fmaf(v.x, v.x, fmaf(v.y, v.y, fmaf(v.z, v.z, fmaf(v.w, v.w, s))));
    }
    float inv = 1.0f / (__builtin_amdgcn_sqrtf(s) + EPS);
    #pragma unroll
    for (int i = 0; i < 16; i++) {
        float4 r  = buf[i];        // dims 4i..4i+3      -> real part
        float4 im = buf[16 + i];   // dims 64+4i..64+4i+3 -> imag part
        float rr[4] = { r.x,  r.y,  r.z,  r.w  };
        float ii[4] = { im.x, im.y, im.z, im.w };
        #pragma unroll
        for (int k = 0; k < 4; k++) {
            float qr = rr[k] * inv;
            float qi = ii[k] * inv;
            float qm = __builtin_amdgcn_sqrtf(fmaf(qr, qr, fmaf(qi, qi, EPS)));
            int f = 4 * i + k;
            QrT[(size_t)f * NUM_QUERIES + q] = qr;   // coalesced: lanes = q
            QiT[(size_t)f * NUM_QUERIES + q] = qi;
            QmT[(size_t)f * NUM_QUERIES + q] = qm;
        }
    }
}

// ---------------------------------------------------------------------------
// Main: block = 128 threads (one per bin), each block owns NQ=16 queries.
// q-side values are wave-uniform -> scalar loads on the SMEM pipe.
// probe side is one coalesced float4 vector load per f.
// Depth-1 software pipeline: loads for f+1 issued before compute of f.
// ---------------------------------------------------------------------------
__global__ __launch_bounds__(NUM_BINS) void main_kernel(
        const float4* __restrict__ probeT,
        const float*  __restrict__ QrT,
        const float*  __restrict__ QiT,
        const float*  __restrict__ QmT,
        const float*  __restrict__ bias,
        float*        __restrict__ out) {
    const int b = threadIdx.x;

    // Bijective XCD swizzle: nwg = 2048 (divisible by 8); each XCD gets a
    // contiguous 256-block chunk of the query range -> q-side cache lines and
    // probe lines stay resident in that XCD's private L2.
    const int nwg   = NUM_QUERIES / NQ;          // 2048
    const int chunk = nwg / 8;                   // 256
    const int wg    = (blockIdx.x & 7) * chunk + (blockIdx.x >> 3);
    const int qbase = wg * NQ;

    float acc[NQ];
    #pragma unroll
    for (int j = 0; j < NQ; j++) acc[j] = 0.0f;

    const float* qrp = QrT + qbase;
    const float* qip = QiT + qbase;
    const float* qmp = QmT + qbase;

    float4 p  = probeT[b];
    f32x16 qr = *reinterpret_cast<const f32x16*>(qrp);
    f32x16 qi = *reinterpret_cast<const f32x16*>(qip);
    f32x16 qm = *reinterpret_cast<const f32x16*>(qmp);

#define COMPUTE_STEP                                                         \
    _Pragma("unroll")                                                        \
    for (int j = 0; j < NQ; j++) {                                           \
        float er = p.x - qr[j];                                              \
        float ei = p.y - qi[j];                                              \
        float d  = __builtin_amdgcn_sqrtf(fmaf(er, er, fmaf(ei, ei, EPS)));  \
        acc[j] = fmaf(d, p.z, fmaf(qm[j], p.w, acc[j]));                     \
    }

    for (int f = 0; f < NUM_FREQS - 1; f++) {
        // prefetch f+1 while computing f
        float4 pn  = probeT[(f + 1) * NUM_BINS + b];
        f32x16 qrn = *reinterpret_cast<const f32x16*>(qrp + (size_t)(f + 1) * NUM_QUERIES);
        f32x16 qin = *reinterpret_cast<const f32x16*>(qip + (size_t)(f + 1) * NUM_QUERIES);
        f32x16 qmn = *reinterpret_cast<const f32x16*>(qmp + (size_t)(f + 1) * NUM_QUERIES);
        COMPUTE_STEP
        p = pn; qr = qrn; qi = qin; qm = qmn;
    }
    COMPUTE_STEP
#undef COMPUTE_STEP

    float bb = bias[b];
    #pragma unroll
    for (int j = 0; j < NQ; j++)
        out[(size_t)(qbase + j) * NUM_BINS + b] = acc[j] + bb;   // coalesced stores
}

// ---------------------------------------------------------------------------
// Fallback (only if ws_size is too small): fully self-contained, slower.
// ---------------------------------------------------------------------------
__global__ void fallback_kernel(const float* __restrict__ Q,
                                const float* __restrict__ rp,
                                const float* __restrict__ wraw,
                                const float* __restrict__ mw,
                                const float* __restrict__ bias,
                                float* __restrict__ out) {
    __shared__ float qn[HEAD_DIM];
    __shared__ float qmag[NUM_FREQS];
    __shared__ float red[NUM_BINS];
    const int t = threadIdx.x;
    const int q = blockIdx.x;

    float v = Q[(size_t)q * HEAD_DIM + t];
    red[t] = v * v;
    __syncthreads();
    for (int s = 64; s > 0; s >>= 1) {
        if (t < s) red[t] += red[t + s];
        __syncthreads();
    }
    float inv = 1.0f / (__builtin_amdgcn_sqrtf(red[0]) + EPS);
    qn[t] = v * inv;
    __syncthreads();
    if (t < NUM_FREQS) {
        float a = qn[t], c = qn[t + NUM_FREQS];
        qmag[t] = __builtin_amdgcn_sqrtf(fmaf(a, a, fmaf(c, c, EPS)));
    }
    __syncthreads();

    const int b = t;
    float acc = 0.0f;
    for (int f = 0; f < NUM_FREQS; f++) {
        float pr = rp[(size_t)b * HEAD_DIM + f];
        float pi = rp[(size_t)b * HEAD_DIM + NUM_FREQS + f];
        float w  = wraw[(size_t)b * NUM_FREQS + f];
        float ew = -(fmaxf(w, 0.0f) + log1pf(expf(-fabsf(w))));
        float er = pr - qn[f];
        float ei = pi - qn[f + NUM_FREQS];
        float d  = __builtin_amdgcn_sqrtf(fmaf(er, er, fmaf(ei, ei, EPS)));
        acc = fmaf(d, ew, fmaf(qmag[f], mw[(size_t)b * NUM_FREQS + f], acc));
    }
    out[(size_t)q * NUM_BINS + b] = acc + bias[b];
}

// ---------------------------------------------------------------------------
extern "C" void kernel_launch(void* const* d_in, const int* in_sizes, int n_in,
                              void* d_out, int out_size, void* d_ws, size_t ws_size,
                              hipStream_t stream) {
    const float* Q    = (const float*)d_in[0];
    const float* rp   = (const float*)d_in[1];
    const float* wraw = (const float*)d_in[2];
    const float* mw   = (const float*)d_in[3];
    const float* bias = (const float*)d_in[4];
    float* out = (float*)d_out;

    const size_t probeBytes = (size_t)NUM_FREQS * NUM_BINS * sizeof(float4);   // 128 KiB
    const size_t qtBytes    = (size_t)NUM_FREQS * NUM_QUERIES * sizeof(float); // 8 MiB
    const size_t need       = probeBytes + 3 * qtBytes;

    if (ws_size >= need) {
        float4* probeT = (float4*)d_ws;
        float*  QrT    = (float*)((char*)d_ws + probeBytes);
        float*  QiT    = QrT + (size_t)NUM_FREQS * NUM_QUERIES;
        float*  QmT    = QiT + (size_t)NUM_FREQS * NUM_QUERIES;

        hipLaunchKernelGGL(prep_probe, dim3((NUM_FREQS * NUM_BINS + 255) / 256),
                           dim3(256), 0, stream, rp, wraw, mw, probeT);
        hipLaunchKernelGGL(prep_q, dim3(NUM_QUERIES / 256), dim3(256), 0, stream,
                           Q, QrT, QiT, QmT);
        hipLaunchKernelGGL(main_kernel, dim3(NUM_QUERIES / NQ), dim3(NUM_BINS), 0,
                           stream, probeT, QrT, QiT, QmT, bias, out);
    } else {
        hipLaunchKernelGGL(fallback_kernel, dim3(NUM_QUERIES), dim3(NUM_BINS), 0,
                           stream, Q, rp, wraw, mw, bias, out);
    }
}